// Round 5
// baseline (72.372 us; speedup 1.0000x reference)
//
#include <hip/hip_runtime.h>

#define NN 2048
#define KK 512

typedef __attribute__((ext_vector_type(8))) short bf16x8;
typedef __attribute__((ext_vector_type(4))) float f32x4;

__device__ inline ushort f2bf(float x) {  // RNE f32->bf16
  union { float f; unsigned u; } v; v.f = x;
  unsigned r = v.u + 0x7fffu + ((v.u >> 16) & 1u);
  return (ushort)(r >> 16);
}

// -------- K1: g = h @ W (f32), 16 rows x 128-k chunk per block. grid 512 ---
// Writes per-kchunk partials: gp[kh], elp[kh], erp[kh]. Summed downstream.
__global__ __launch_bounds__(256) void k_gemm(
    const float* __restrict__ hin, const float* __restrict__ W,
    const float* __restrict__ aw, float* __restrict__ gp,
    float* __restrict__ elp, float* __restrict__ erp) {
  __shared__ float hs[16][132];
  const int tid = threadIdx.x;
  const int ib = blockIdx.x >> 2;
  const int kh = blockIdx.x & 3;
  const int i0 = ib * 16;
  const int k0 = kh * 128;

#pragma unroll
  for (int p = 0; p < 2; ++p) {
    int idx = tid + p * 256;       // float4 index, 0..511
    int row = idx >> 5;            // 32 float4 per row
    int c4 = (idx & 31) << 2;
    *(float4*)&hs[row][c4] = *(const float4*)(hin + (size_t)(i0 + row) * KK + k0 + c4);
  }
  __syncthreads();

  float acc[16];
#pragma unroll
  for (int r = 0; r < 16; ++r) acc[r] = 0.f;

#pragma unroll 4
  for (int k = 0; k < 128; ++k) {
    float wk = W[(size_t)(k0 + k) * 256 + tid];
#pragma unroll
    for (int r = 0; r < 16; ++r) acc[r] += hs[r][k] * wk;
  }

  float* go = gp + (size_t)kh * (NN * 256);
#pragma unroll
  for (int r = 0; r < 16; ++r) go[(size_t)(i0 + r) * 256 + tid] = acc[r];

  const int lane = tid & 63;
  const int w = tid >> 6;  // head
  const float asrc = aw[lane];
  const float adst = aw[64 + lane];
#pragma unroll
  for (int r = 0; r < 16; ++r) {
    float e1 = acc[r] * asrc;
    float e2 = acc[r] * adst;
#pragma unroll
    for (int m = 1; m < 64; m <<= 1) {
      e1 += __shfl_xor(e1, m);
      e2 += __shfl_xor(e2, m);
    }
    if (lane == 0) {
      elp[kh * 8192 + (i0 + r) * 4 + w] = e1;
      erp[kh * 8192 + (i0 + r) * 4 + w] = e2;
    }
  }
}

// -------- K2a: sum el/er partials, build exp tables. grid 8 --------
__global__ __launch_bounds__(256) void k_tables(
    const float* __restrict__ elp, const float* __restrict__ erp,
    float* __restrict__ Eel, float* __restrict__ Fel,
    float* __restrict__ Eer_jh, float* __restrict__ Fer_jh,
    float* __restrict__ Eer_hj, float* __restrict__ Fer_hj) {
  const int idx = blockIdx.x * 256 + threadIdx.x;
  float el_[4] = {0.f, 0.f, 0.f, 0.f};
  float er_[4] = {0.f, 0.f, 0.f, 0.f};
#pragma unroll
  for (int kh = 0; kh < 4; ++kh) {
    float4 e4 = *(const float4*)(elp + kh * 8192 + idx * 4);
    float4 r4 = *(const float4*)(erp + kh * 8192 + idx * 4);
    el_[0] += e4.x; el_[1] += e4.y; el_[2] += e4.z; el_[3] += e4.w;
    er_[0] += r4.x; er_[1] += r4.y; er_[2] += r4.z; er_[3] += r4.w;
  }
  float eel[4], fel[4], eer[4], fer[4];
#pragma unroll
  for (int h = 0; h < 4; ++h) {
    eel[h] = __expf(el_[h]);
    fel[h] = __expf(0.2f * el_[h]);
    eer[h] = __expf(er_[h]);
    fer[h] = __expf(0.2f * er_[h]);
  }
  *(float4*)(Eel + idx * 4) = make_float4(eel[0], eel[1], eel[2], eel[3]);
  *(float4*)(Fel + idx * 4) = make_float4(fel[0], fel[1], fel[2], fel[3]);
  *(float4*)(Eer_jh + idx * 4) = make_float4(eer[0], eer[1], eer[2], eer[3]);
  *(float4*)(Fer_jh + idx * 4) = make_float4(fer[0], fer[1], fer[2], fer[3]);
#pragma unroll
  for (int h = 0; h < 4; ++h) {
    Eer_hj[h * NN + idx] = eer[h];
    Fer_hj[h * NN + idx] = fer[h];
  }
}

// -------- K2b: gTb (tiled bf16: [j/8][f][8]) from summed g partials. grid 128
__global__ __launch_bounds__(256) void k_prep(
    const float* __restrict__ gp, ushort* __restrict__ gTb) {
  __shared__ float ts[64][65];
  const int bx = blockIdx.x;
  const int t = threadIdx.x;
  const int r0 = (bx >> 2) * 64;   // j block
  const int c0 = (bx & 3) * 64;    // f block
  const int tr = t >> 6;           // 0..3
  const int tc = t & 63;
#pragma unroll
  for (int i = 0; i < 16; ++i) {
    size_t off = (size_t)(r0 + tr + i * 4) * 256 + c0 + tc;
    float v = gp[off] + gp[off + (size_t)(NN * 256)] +
              gp[off + (size_t)(2 * NN * 256)] + gp[off + (size_t)(3 * NN * 256)];
    ts[tr + i * 4][tc] = v;
  }
  __syncthreads();
#pragma unroll
  for (int i = 0; i < 16; ++i) {
    float v = ts[tc][tr + i * 4];          // = g[r0+tc][c0+tr+i*4]
    const int j = r0 + tc;
    const int f = c0 + tr + i * 4;
    gTb[(size_t)(j >> 3) * 2048 + f * 8 + (j & 7)] = f2bf(v);
  }
}

// -------- K3: Z1[h], Z2 + adjacency bitmask. grid 2048 (block = row) -------
__global__ __launch_bounds__(256) void k_rowz(
    const float* __restrict__ adj, const float* __restrict__ s,
    const float* __restrict__ Eel, const float* __restrict__ Fel,
    const float* __restrict__ Eer_jh, const float* __restrict__ Fer_jh,
    float* __restrict__ rZ1, float* __restrict__ rZ2,
    unsigned long long* __restrict__ maskb) {
  const int row = blockIdx.x;
  const int tid = threadIdx.x;
  const int wq = tid >> 6;
  const int lane = tid & 63;

  float4 e4 = *(const float4*)(Eel + row * 4);
  float4 f4 = *(const float4*)(Fel + row * 4);
  const float eel[4] = {e4.x, e4.y, e4.z, e4.w};
  const float fel[4] = {f4.x, f4.y, f4.z, f4.w};

  float z1[4] = {0.f, 0.f, 0.f, 0.f};
  float z2 = 0.f;

  const float* ap = adj + (size_t)row * NN + wq * 512;
  const float* sp = s + (size_t)row * NN + wq * 512;

#pragma unroll
  for (int it = 0; it < 8; ++it) {
    const int j = it * 64 + lane;
    float a = ap[j];
    float sv = sp[j];
    bool nb = (a != 0.f);
    unsigned long long m = __ballot(nb);
    if (lane == 0) maskb[row * 32 + wq * 8 + it] = m;
    const int jg = wq * 512 + j;
    float4 eer4 = *(const float4*)(Eer_jh + jg * 4);
    float4 fer4 = *(const float4*)(Fer_jh + jg * 4);
    z2 += nb ? __expf(sv) : 0.f;
    float ev[4] = {eer4.x, eer4.y, eer4.z, eer4.w};
    float fv[4] = {fer4.x, fer4.y, fer4.z, fer4.w};
#pragma unroll
    for (int h = 0; h < 4; ++h) {
      float p = eel[h] * ev[h];
      float q = fel[h] * fv[h];
      float E = (p > 1.f) ? p : q;
      z1[h] += nb ? E : 0.f;
    }
  }

#pragma unroll
  for (int m = 1; m < 64; m <<= 1) {
    z2 += __shfl_xor(z2, m);
#pragma unroll
    for (int h = 0; h < 4; ++h) z1[h] += __shfl_xor(z1[h], m);
  }

  __shared__ float wr[4][5];
  if (lane == 0) {
    wr[wq][0] = z1[0]; wr[wq][1] = z1[1]; wr[wq][2] = z1[2]; wr[wq][3] = z1[3];
    wr[wq][4] = z2;
  }
  __syncthreads();
  if (tid < 5) {
    float sum = wr[0][tid] + wr[1][tid] + wr[2][tid] + wr[3][tid];
    if (tid < 4) rZ1[row * 4 + tid] = 1.f / sum;
    else rZ2[row] = 1.f / sum;
  }
}

// -------- K4: coefficient + MFMA contraction. grid 1024 (8 j-chunks) ------
// wave = head h; lane: il = lane&15 (i-row), kg = lane>>4 (k-group)
__global__ __launch_bounds__(256, 8) void k_attn(
    const float* __restrict__ s, const unsigned long long* __restrict__ maskb,
    const ushort* __restrict__ gTb,
    const float* __restrict__ Eel, const float* __restrict__ Fel,
    const float* __restrict__ Eer_hj, const float* __restrict__ Fer_hj,
    const float* __restrict__ rZ1, const float* __restrict__ rZ2,
    _Float16* __restrict__ U, float* __restrict__ Z3p) {
  const int tid = threadIdx.x;
  const int h = tid >> 6;
  const int lane = tid & 63;
  const int il = lane & 15;
  const int kg = lane >> 4;
  const int ib = blockIdx.x >> 3;
  const int jc = blockIdx.x & 7;
  const int i0 = ib * 16;
  const int jb0 = jc * 256;
  const int row = i0 + il;

  const float eel = Eel[row * 4 + h];
  const float fel = Fel[row * 4 + h];
  const float rz1 = rZ1[row * 4 + h];
  const float rz2 = rZ2[row];

  const unsigned long long* mp = maskb + row * 32 + jc * 4;
  const unsigned long long m0 = mp[0];
  const unsigned long long m1 = mp[1];
  const unsigned long long m2 = mp[2];
  const unsigned long long m3 = mp[3];

  f32x4 acc[4];
#pragma unroll
  for (int nt = 0; nt < 4; ++nt) acc[nt] = (f32x4){0.f, 0.f, 0.f, 0.f};
  float z3 = 0.f;

  const float* sp = s + (size_t)row * NN + jb0 + kg * 8;
  const float* eerp = Eer_hj + h * NN + jb0 + kg * 8;
  const float* ferp = Fer_hj + h * NN + jb0 + kg * 8;
  const ushort* bp = gTb + (size_t)(jc * 32 + kg) * 2048 + (h * 64 + il) * 8;

#pragma unroll
  for (int ks = 0; ks < 8; ++ks) {
    const int o = ks * 32;
    unsigned long long w = (ks >> 1) == 0 ? m0
                         : (ks >> 1) == 1 ? m1
                         : (ks >> 1) == 2 ? m2 : m3;
    unsigned byte_ = (unsigned)(w >> ((ks & 1) * 32 + kg * 8)) & 0xffu;

    bf16x8 A;
#pragma unroll
    for (int gp = 0; gp < 2; ++gp) {
      float4 s4 = *(const float4*)(sp + o + gp * 4);
      float4 ee4 = *(const float4*)(eerp + o + gp * 4);
      float4 fe4 = *(const float4*)(ferp + o + gp * 4);
      float sv[4] = {s4.x, s4.y, s4.z, s4.w};
      float ev[4] = {ee4.x, ee4.y, ee4.z, ee4.w};
      float fv[4] = {fe4.x, fe4.y, fe4.z, fe4.w};
#pragma unroll
      for (int e = 0; e < 4; ++e) {
        bool nb = (byte_ >> (gp * 4 + e)) & 1u;
        float spv = __expf(sv[e]) * rz2;
        float p = eel * ev[e];
        float q = fel * fv[e];
        float E = (p > 1.f) ? p : q;
        float tt = nb ? (E * rz1 + spv) : 0.f;
        float c = __expf(tt);
        z3 += c;
        A[gp * 4 + e] = (short)f2bf(c);
      }
    }

    const ushort* bks = bp + (size_t)(ks * 4) * 2048;
    acc[0] = __builtin_amdgcn_mfma_f32_16x16x32_bf16(A, *(const bf16x8*)(bks), acc[0], 0, 0, 0);
    acc[1] = __builtin_amdgcn_mfma_f32_16x16x32_bf16(A, *(const bf16x8*)(bks + 128), acc[1], 0, 0, 0);
    acc[2] = __builtin_amdgcn_mfma_f32_16x16x32_bf16(A, *(const bf16x8*)(bks + 256), acc[2], 0, 0, 0);
    acc[3] = __builtin_amdgcn_mfma_f32_16x16x32_bf16(A, *(const bf16x8*)(bks + 384), acc[3], 0, 0, 0);
  }

  z3 += __shfl_xor(z3, 16);
  z3 += __shfl_xor(z3, 32);
  if (lane < 16)
    Z3p[jc * (NN * 4) + (i0 + lane) * 4 + h] = z3;

  _Float16* up = U + (size_t)jc * (NN * 256) + (size_t)i0 * 256 + h * 64 + il;
#pragma unroll
  for (int nt = 0; nt < 4; ++nt)
#pragma unroll
    for (int q = 0; q < 4; ++q)
      up[(size_t)(kg * 4 + q) * 256 + nt * 16] = (_Float16)acc[nt][q];
}

// -------- K5: combine 8 partials, divide by Z3 --------
__global__ __launch_bounds__(256) void k_final(
    const _Float16* __restrict__ U, const float* __restrict__ Z3p,
    float* __restrict__ out) {
  const int i = blockIdx.x;
  const int c = threadIdx.x;
  const int h = c >> 6;
  float u = 0.f, z = 0.f;
#pragma unroll
  for (int p = 0; p < 8; ++p) {
    u += (float)U[(size_t)p * (NN * 256) + (size_t)i * 256 + c];
    z += Z3p[p * (NN * 4) + i * 4 + h];
  }
  out[(size_t)i * 256 + c] = u / z;
}

extern "C" void kernel_launch(void* const* d_in, const int* in_sizes, int n_in,
                              void* d_out, int out_size, void* d_ws, size_t ws_size,
                              hipStream_t stream) {
  const float* hin = (const float*)d_in[0];
  const float* adj = (const float*)d_in[1];
  const float* s = (const float*)d_in[2];
  const float* W = (const float*)d_in[3];
  const float* aw = (const float*)d_in[4];
  float* out = (float*)d_out;

  float* ws = (float*)d_ws;
  float* gp     = ws;                       // 4 * 524288 = 2097152
  float* elp    = ws + 2097152;             // 4 * 8192 = 32768
  float* erp    = ws + 2129920;             // 32768
  float* Eel    = ws + 2162688;             // 8192
  float* Fel    = ws + 2170880;             // 8192
  float* Eer_jh = ws + 2179072;             // 8192
  float* Fer_jh = ws + 2187264;             // 8192
  float* Eer_hj = ws + 2195456;             // 8192
  float* Fer_hj = ws + 2203648;             // 8192
  float* rZ1    = ws + 2211840;             // 8192
  float* rZ2    = ws + 2220032;             // 2048
  float* Z3p    = ws + 2222080;             // 8 * 8192 = 65536
  unsigned long long* maskb = (unsigned long long*)(ws + 2287616);  // 65536 u64 = 131072 slots
  ushort* gTb   = (ushort*)(ws + 2418688);  // 524288 ushorts = 262144 slots
  _Float16* U   = (_Float16*)(ws + 2680832); // 8 * 1048576 f16 = 2097152 slots

  k_gemm<<<512, 256, 0, stream>>>(hin, W, aw, gp, elp, erp);
  k_tables<<<8, 256, 0, stream>>>(elp, erp, Eel, Fel, Eer_jh, Fer_jh, Eer_hj, Fer_hj);
  k_prep<<<128, 256, 0, stream>>>(gp, gTb);
  k_rowz<<<2048, 256, 0, stream>>>(adj, s, Eel, Fel, Eer_jh, Fer_jh, rZ1, rZ2, maskb);
  k_attn<<<1024, 256, 0, stream>>>(s, maskb, gTb, Eel, Fel, Eer_hj, Fer_hj, rZ1, rZ2, U, Z3p);
  k_final<<<2048, 256, 0, stream>>>(U, Z3p, out);
}